// Round 2
// baseline (34522.229 us; speedup 1.0000x reference)
//
#include <hip/hip_runtime.h>
#include <math.h>

#define B_  8
#define S_  16
#define H_  32
#define W_  32
#define E_  128
#define NH_ 8
#define HD_ 16
#define HW_ (H_*W_)            // 1024
#define NTOK (B_*S_*H_*W_)     // 131072

__device__ __forceinline__ float sigf(float x){
    return 1.f/(1.f+__expf(-x));
}
__device__ __forceinline__ float tanh_fast(float x){
    x = fminf(fmaxf(x, -15.f), 15.f);
    float e = __expf(2.f*x);
    return (e-1.f)/(e+1.f);
}
__device__ __forceinline__ void fma4(float4& a, float v, const float4 w){
    a.x += v*w.x; a.y += v*w.y; a.z += v*w.z; a.w += v*w.w;
}

// ---------------------------------------------------------------------------
// conv_k (512,256,3,3) OIHW  ->  wt[(tap*256+ic)*512 + oc]
__global__ __launch_bounds__(256)
void k_transpose_w(const float* __restrict__ ck, float* __restrict__ wt){
    int idx = blockIdx.x*256 + threadIdx.x;            // 9*256*512 exact
    int oc  = idx & 511;
    int rem = idx >> 9;                                // tap*256+ic
    int ic  = rem & 255;
    int tap = rem >> 8;
    int dy = tap/3, dx = tap%3;
    wt[idx] = ck[((oc*256+ic)*3+dy)*3+dx];
}

// ---------------------------------------------------------------------------
// X = LayerNorm(silu(inputs @ W_proj)) ; 8 rows per block, 128 threads
__global__ __launch_bounds__(128)
void k_proj_ln(const float* __restrict__ in, const float* __restrict__ Wp,
               const float* __restrict__ gamma, const float* __restrict__ beta,
               float* __restrict__ X){
    __shared__ float xin[8][128];
    __shared__ float red[2][8][2];
    int tid = threadIdx.x;
    long r0 = (long)blockIdx.x * 8;
    #pragma unroll
    for (int r=0;r<8;r++) xin[r][tid] = in[(r0+r)*128 + tid];
    __syncthreads();

    float acc[8] = {0,0,0,0,0,0,0,0};
    for (int k=0;k<128;k+=4){
        float w0 = Wp[(k+0)*128+tid];
        float w1 = Wp[(k+1)*128+tid];
        float w2 = Wp[(k+2)*128+tid];
        float w3 = Wp[(k+3)*128+tid];
        #pragma unroll
        for (int r=0;r<8;r++){
            float4 xv = *(const float4*)&xin[r][k];
            acc[r] += xv.x*w0 + xv.y*w1 + xv.z*w2 + xv.w*w3;
        }
    }
    #pragma unroll
    for (int r=0;r<8;r++){ float a = acc[r]; acc[r] = a*sigf(a); }   // silu

    int lane = tid & 63, wid = tid >> 6;
    #pragma unroll
    for (int r=0;r<8;r++){
        float s1 = acc[r], s2 = acc[r]*acc[r];
        #pragma unroll
        for (int off=32; off>0; off>>=1){
            s1 += __shfl_down(s1, off);
            s2 += __shfl_down(s2, off);
        }
        if (lane==0){ red[wid][r][0] = s1; red[wid][r][1] = s2; }
    }
    __syncthreads();
    float g = gamma[tid], bb = beta[tid];
    #pragma unroll
    for (int r=0;r<8;r++){
        float s1 = red[0][r][0] + red[1][r][0];
        float s2 = red[0][r][1] + red[1][r][1];
        float mu  = s1 * (1.f/128.f);
        float var = s2 * (1.f/128.f) - mu*mu;
        float y = (acc[r]-mu)*rsqrtf(var + 1e-5f)*g + bb;
        X[(r0+r)*128 + tid] = y;
    }
}

// ---------------------------------------------------------------------------
// One block per (b,h,w): qkv = x@W_in, causal softmax attn, ao@W_out + resid.
// Writes result IN PLACE over X (rows are block-disjoint).
__global__ __launch_bounds__(384)
void k_attn(const float* __restrict__ X, const float* __restrict__ Win,
            const float* __restrict__ Wout, const float* __restrict__ resid,
            float* __restrict__ Y){
    __shared__ float xs[16][128];
    __shared__ float qkv[16][385];          // pad: 385%32==1 -> no bank clash on sj
    __shared__ float sc[8][16][16];
    __shared__ float ao[16][128];
    int tid = threadIdx.x;
    int blk = blockIdx.x;
    int b  = blk >> 10;
    int hw = blk & 1023;
    long base0 = ((long)(b*16)*1024 + hw) * 128;     // s=0 row, float index
    const long sstride = (long)HW_ * 128;            // per-s stride

    for (int idx=tid; idx<2048; idx+=384){
        int s = idx >> 7, e = idx & 127;
        xs[s][e] = X[base0 + (long)s*sstride + e];
    }
    __syncthreads();

    { // qkv: thread j owns one of 384 output columns, all 16 s
        int j = tid;
        float acc[16];
        #pragma unroll
        for (int s=0;s<16;s++) acc[s] = 0.f;
        for (int k=0;k<128;k+=4){
            float w0 = Win[(k+0)*384 + j];
            float w1 = Win[(k+1)*384 + j];
            float w2 = Win[(k+2)*384 + j];
            float w3 = Win[(k+3)*384 + j];
            #pragma unroll
            for (int s=0;s<16;s++){
                float4 xv = *(const float4*)&xs[s][k];
                acc[s] += xv.x*w0 + xv.y*w1 + xv.z*w2 + xv.w*w3;
            }
        }
        #pragma unroll
        for (int s=0;s<16;s++) qkv[s][j] = acc[s];
    }
    __syncthreads();

    const float scale = 0.25f;               // 1/sqrt(16)
    for (int idx=tid; idx<2048; idx+=384){   // scores + mask
        int i = idx >> 8; int rem = idx & 255; int si = rem >> 4, sj = rem & 15;
        float a = 0.f;
        #pragma unroll
        for (int d=0;d<16;d++) a += qkv[si][i*48+d]*qkv[sj][i*48+16+d];
        a = a*scale + (sj <= si ? 1.0f : -1000.0f);
        sc[i][si][sj] = a;
    }
    __syncthreads();

    if (tid < 128){                          // softmax rows
        int i = tid >> 4, si = tid & 15;
        float* row = sc[i][si];
        float m = -1e30f;
        #pragma unroll
        for (int j=0;j<16;j++) m = fmaxf(m, row[j]);
        float ev[16], sum = 0.f;
        #pragma unroll
        for (int j=0;j<16;j++){ ev[j] = __expf(row[j]-m); sum += ev[j]; }
        float inv = 1.f/sum;
        #pragma unroll
        for (int j=0;j<16;j++) row[j] = ev[j]*inv;
    }
    __syncthreads();

    for (int idx=tid; idx<2048; idx+=384){   // ao = attnw @ v
        int s = idx >> 7, c = idx & 127; int i = c >> 4, d = c & 15;
        float a = 0.f;
        #pragma unroll
        for (int sj=0;sj<16;sj++) a += sc[i][s][sj]*qkv[sj][i*48+32+d];
        ao[s][c] = a;
    }
    __syncthreads();

    for (int idx=tid; idx<2048; idx+=384){   // ao @ W_out + residual
        int s = idx >> 7, e = idx & 127;
        float a = 0.f;
        for (int k=0;k<128;k+=4){
            float4 av = *(const float4*)&ao[s][k];
            a += av.x*Wout[(k+0)*128+e] + av.y*Wout[(k+1)*128+e]
               + av.z*Wout[(k+2)*128+e] + av.w*Wout[(k+3)*128+e];
        }
        long off = base0 + (long)s*sstride + e;
        Y[off] = a + resid[off];
    }
}

// ---------------------------------------------------------------------------
// Copy time-slice s of X (d_out layout) into a compact ws buffer
__global__ __launch_bounds__(256)
void k_slice(const float* __restrict__ xres, float* __restrict__ xs, int s){
    int idx = blockIdx.x*256 + threadIdx.x;         // over B*HW*32 = 262144 float4
    int per_b = HW_*32;                             // float4 per (b,s) slice
    int b = idx / per_b;
    int r = idx - b*per_b;
    const float4* src = (const float4*)xres;
    ((float4*)xs)[idx] = src[(long)(b*16+s)*per_b + r];
}

// ---------------------------------------------------------------------------
// One ConvLSTM step. One block per (b,y) row (256 blocks), 256 thr = 32 x * 8 oct.
// Each thread: 16 oc per gate x 4 gates = 64 accumulators, K=2304.
// h_prev is read from X slice (s-1) (h written there by previous step);
// h_next is written to X slice s. c kept in compact ws buffer, zero-init at s==0.
__global__ __launch_bounds__(256)
void k_conv(const float* __restrict__ xs, float* __restrict__ X,
            float* __restrict__ c, const float* __restrict__ wt, int s){
    int b = blockIdx.x >> 5, y = blockIdx.x & 31;
    int tid = threadIdx.x;
    int x = tid >> 3, oct = tid & 7;

    float4 acc[4][4];
    #pragma unroll
    for (int g=0;g<4;g++)
        #pragma unroll
        for (int q=0;q<4;q++) acc[g][q] = make_float4(0.f,0.f,0.f,0.f);

    for (int dy=-1; dy<=1; dy++){
        int yy = y + dy;
        bool yok = (yy >= 0) & (yy < 32);
        for (int dx=-1; dx<=1; dx++){
            int xx = x + dx;
            bool ok = yok & (xx >= 0) & (xx < 32);
            if (!ok) continue;                         // zero padding: skip
            int tap = (dy+1)*3 + (dx+1);
            int posc = ((b*32+yy)*32+xx)*128;          // compact plane index
            const float* xp = xs + posc;
            const float* wb = wt + tap*256*512 + oct*16;
            for (int ic=0; ic<128; ic+=4){
                float4 v4 = *(const float4*)(xp + ic);
                float vv[4] = {v4.x, v4.y, v4.z, v4.w};
                #pragma unroll
                for (int u=0;u<4;u++){
                    const float* wr = wb + (ic+u)*512;
                    #pragma unroll
                    for (int g=0;g<4;g++){
                        #pragma unroll
                        for (int q=0;q<4;q++)
                            fma4(acc[g][q], vv[u], *(const float4*)(wr + g*128 + q*4));
                    }
                }
            }
            if (s > 0){                                // h0 == 0: skip at s==0
                const float* hp = X + ((((long)(b*16+(s-1))*32+yy)*32+xx)*128);
                for (int ic=0; ic<128; ic+=4){
                    float4 v4 = *(const float4*)(hp + ic);
                    float vv[4] = {v4.x, v4.y, v4.z, v4.w};
                    #pragma unroll
                    for (int u=0;u<4;u++){
                        const float* wr = wb + (128+ic+u)*512;
                        #pragma unroll
                        for (int g=0;g<4;g++){
                            #pragma unroll
                            for (int q=0;q<4;q++)
                                fma4(acc[g][q], vv[u], *(const float4*)(wr + g*128 + q*4));
                        }
                    }
                }
            }
        }
    }

    // gates: oc = g*128 + oct*16 + q*4 + comp
    int pos = ((b*32+y)*32+x)*128 + oct*16;
    long opos = ((((long)(b*16+s)*32+y)*32+x)*128) + oct*16;
    #pragma unroll
    for (int q=0;q<4;q++){
        float4 civ = acc[0][q], cfv = acc[1][q], cov = acc[2][q], cgv = acc[3][q];
        float4 cold;
        if (s == 0) cold = make_float4(0.f,0.f,0.f,0.f);
        else        cold = *(const float4*)&c[pos + q*4];
        float4 cn, hn;
        cn.x = sigf(cfv.x)*cold.x + sigf(civ.x)*tanh_fast(cgv.x);
        cn.y = sigf(cfv.y)*cold.y + sigf(civ.y)*tanh_fast(cgv.y);
        cn.z = sigf(cfv.z)*cold.z + sigf(civ.z)*tanh_fast(cgv.z);
        cn.w = sigf(cfv.w)*cold.w + sigf(civ.w)*tanh_fast(cgv.w);
        hn.x = sigf(cov.x)*tanh_fast(cn.x);
        hn.y = sigf(cov.y)*tanh_fast(cn.y);
        hn.z = sigf(cov.z)*tanh_fast(cn.z);
        hn.w = sigf(cov.w)*tanh_fast(cn.w);
        *(float4*)&c[pos + q*4] = cn;
        *(float4*)&X[opos + q*4] = hn;
    }
}

// ---------------------------------------------------------------------------
extern "C" void kernel_launch(void* const* d_in, const int* in_sizes, int n_in,
                              void* d_out, int out_size, void* d_ws, size_t ws_size,
                              hipStream_t stream){
    const float* inputs = (const float*)d_in[0];
    const float* Wp     = (const float*)d_in[1];
    const float* gamma  = (const float*)d_in[2];
    const float* beta   = (const float*)d_in[3];
    const float* Win    = (const float*)d_in[4];
    const float* Wout   = (const float*)d_in[5];
    const float* ck     = (const float*)d_in[6];
    float* X = (float*)d_out;

    const size_t plane = (size_t)B_*HW_*128*sizeof(float);   // 4 MB
    char* ws = (char*)d_ws;
    float* xs_step = (float*)(ws);                           // 4 MB
    float* cbuf    = (float*)(ws + plane);                   // 4 MB
    float* wt      = (float*)(ws + 2*plane);                 // 512*2304*4 = 4.5 MB
    // total ws need: 12.5 MB

    k_transpose_w<<<4608, 256, 0, stream>>>(ck, wt);
    k_proj_ln<<<NTOK/8, 128, 0, stream>>>(inputs, Wp, gamma, beta, X);
    k_attn<<<B_*HW_, 384, 0, stream>>>(X, Win, Wout, inputs, X);  // in-place
    for (int s=0; s<16; s++){
        k_slice<<<(B_*HW_*32)/256, 256, 0, stream>>>(X, xs_step, s);
        k_conv<<<B_*H_, 256, 0, stream>>>(xs_step, X, cbuf, wt, s);
    }
}

// Round 3
// 2035.537 us; speedup vs baseline: 16.9598x; 16.9598x over previous
//
#include <hip/hip_runtime.h>
#include <math.h>

#define B_  8
#define S_  16
#define H_  32
#define W_  32
#define E_  128
#define NH_ 8
#define HD_ 16
#define HW_ (H_*W_)            // 1024
#define NTOK (B_*S_*H_*W_)     // 131072

typedef __attribute__((ext_vector_type(8))) short short8;
typedef __attribute__((ext_vector_type(4))) float floatx4;

__device__ __forceinline__ float sigf(float x){
    return 1.f/(1.f+__expf(-x));
}
__device__ __forceinline__ float tanh_fast(float x){
    x = fminf(fmaxf(x, -15.f), 15.f);
    float e = __expf(2.f*x);
    return (e-1.f)/(e+1.f);
}
__device__ __forceinline__ unsigned short f2bf(float f){
    unsigned int u = __float_as_uint(f);
    u = (u + 0x7fffu + ((u >> 16) & 1u)) >> 16;   // RNE
    return (unsigned short)u;
}
__device__ __forceinline__ float bf2f(unsigned short h){
    return __uint_as_float(((unsigned int)h) << 16);
}

// gate store/load overloads (fp32 scratch if ws allows, else bf16)
__device__ __forceinline__ void st_gate(float* p, float v){ *p = v; }
__device__ __forceinline__ void st_gate(unsigned short* p, float v){ *p = f2bf(v); }
__device__ __forceinline__ void load_gate(const float* p, float* o){
    float4 v = *(const float4*)p; o[0]=v.x; o[1]=v.y; o[2]=v.z; o[3]=v.w;
}
__device__ __forceinline__ void load_gate(const unsigned short* p, float* o){
    ushort4 v = *(const ushort4*)p;
    o[0]=bf2f(v.x); o[1]=bf2f(v.y); o[2]=bf2f(v.z); o[3]=bf2f(v.w);
}

// ---------------------------------------------------------------------------
// X = LayerNorm(silu(inputs @ W_proj)) ; 8 rows per block, 128 threads
__global__ __launch_bounds__(128)
void k_proj_ln(const float* __restrict__ in, const float* __restrict__ Wp,
               const float* __restrict__ gamma, const float* __restrict__ beta,
               float* __restrict__ X){
    __shared__ float xin[8][128];
    __shared__ float red[2][8][2];
    int tid = threadIdx.x;
    long r0 = (long)blockIdx.x * 8;
    #pragma unroll
    for (int r=0;r<8;r++) xin[r][tid] = in[(r0+r)*128 + tid];
    __syncthreads();

    float acc[8] = {0,0,0,0,0,0,0,0};
    for (int k=0;k<128;k+=4){
        float w0 = Wp[(k+0)*128+tid];
        float w1 = Wp[(k+1)*128+tid];
        float w2 = Wp[(k+2)*128+tid];
        float w3 = Wp[(k+3)*128+tid];
        #pragma unroll
        for (int r=0;r<8;r++){
            float4 xv = *(const float4*)&xin[r][k];
            acc[r] += xv.x*w0 + xv.y*w1 + xv.z*w2 + xv.w*w3;
        }
    }
    #pragma unroll
    for (int r=0;r<8;r++){ float a = acc[r]; acc[r] = a*sigf(a); }   // silu

    int lane = tid & 63, wid = tid >> 6;
    #pragma unroll
    for (int r=0;r<8;r++){
        float s1 = acc[r], s2 = acc[r]*acc[r];
        #pragma unroll
        for (int off=32; off>0; off>>=1){
            s1 += __shfl_down(s1, off);
            s2 += __shfl_down(s2, off);
        }
        if (lane==0){ red[wid][r][0] = s1; red[wid][r][1] = s2; }
    }
    __syncthreads();
    float g = gamma[tid], bb = beta[tid];
    #pragma unroll
    for (int r=0;r<8;r++){
        float s1 = red[0][r][0] + red[1][r][0];
        float s2 = red[0][r][1] + red[1][r][1];
        float mu  = s1 * (1.f/128.f);
        float var = s2 * (1.f/128.f) - mu*mu;
        float y = (acc[r]-mu)*rsqrtf(var + 1e-5f)*g + bb;
        X[(r0+r)*128 + tid] = y;
    }
}

// ---------------------------------------------------------------------------
// One block per (b,h,w): qkv = x@W_in, causal softmax attn, ao@W_out + resid.
// Writes result IN PLACE over X (rows are block-disjoint).
__global__ __launch_bounds__(384)
void k_attn(const float* __restrict__ X, const float* __restrict__ Win,
            const float* __restrict__ Wout, const float* __restrict__ resid,
            float* __restrict__ Y){
    __shared__ float xs[16][128];
    __shared__ float qkv[16][385];
    __shared__ float sc[8][16][16];
    __shared__ float ao[16][128];
    int tid = threadIdx.x;
    int blk = blockIdx.x;
    int b  = blk >> 10;
    int hw = blk & 1023;
    long base0 = ((long)(b*16)*1024 + hw) * 128;
    const long sstride = (long)HW_ * 128;

    for (int idx=tid; idx<2048; idx+=384){
        int s = idx >> 7, e = idx & 127;
        xs[s][e] = X[base0 + (long)s*sstride + e];
    }
    __syncthreads();

    {
        int j = tid;
        float acc[16];
        #pragma unroll
        for (int s=0;s<16;s++) acc[s] = 0.f;
        for (int k=0;k<128;k+=4){
            float w0 = Win[(k+0)*384 + j];
            float w1 = Win[(k+1)*384 + j];
            float w2 = Win[(k+2)*384 + j];
            float w3 = Win[(k+3)*384 + j];
            #pragma unroll
            for (int s=0;s<16;s++){
                float4 xv = *(const float4*)&xs[s][k];
                acc[s] += xv.x*w0 + xv.y*w1 + xv.z*w2 + xv.w*w3;
            }
        }
        #pragma unroll
        for (int s=0;s<16;s++) qkv[s][j] = acc[s];
    }
    __syncthreads();

    const float scale = 0.25f;
    for (int idx=tid; idx<2048; idx+=384){
        int i = idx >> 8; int rem = idx & 255; int si = rem >> 4, sj = rem & 15;
        float a = 0.f;
        #pragma unroll
        for (int d=0;d<16;d++) a += qkv[si][i*48+d]*qkv[sj][i*48+16+d];
        a = a*scale + (sj <= si ? 1.0f : -1000.0f);
        sc[i][si][sj] = a;
    }
    __syncthreads();

    if (tid < 128){
        int i = tid >> 4, si = tid & 15;
        float* row = sc[i][si];
        float m = -1e30f;
        #pragma unroll
        for (int j=0;j<16;j++) m = fmaxf(m, row[j]);
        float ev[16], sum = 0.f;
        #pragma unroll
        for (int j=0;j<16;j++){ ev[j] = __expf(row[j]-m); sum += ev[j]; }
        float inv = 1.f/sum;
        #pragma unroll
        for (int j=0;j<16;j++) row[j] = ev[j]*inv;
    }
    __syncthreads();

    for (int idx=tid; idx<2048; idx+=384){
        int s = idx >> 7, c = idx & 127; int i = c >> 4, d = c & 15;
        float a = 0.f;
        #pragma unroll
        for (int sj=0;sj<16;sj++) a += sc[i][s][sj]*qkv[sj][i*48+32+d];
        ao[s][c] = a;
    }
    __syncthreads();

    for (int idx=tid; idx<2048; idx+=384){
        int s = idx >> 7, e = idx & 127;
        float a = 0.f;
        for (int k=0;k<128;k+=4){
            float4 av = *(const float4*)&ao[s][k];
            a += av.x*Wout[(k+0)*128+e] + av.y*Wout[(k+1)*128+e]
               + av.z*Wout[(k+2)*128+e] + av.w*Wout[(k+3)*128+e];
        }
        long off = base0 + (long)s*sstride + e;
        Y[off] = a + resid[off];
    }
}

// ---------------------------------------------------------------------------
// Weights -> B-fragment packets, bf16.
// Bp packet p = ((tap*8 + c32)*32 + nt)*64 + L holds, for j in [0,8):
//   B[k = tap*256 + c32*32 + (L>>4)*8 + j][oc = nt*16 + (L&15)]
__global__ __launch_bounds__(256)
void k_pack_w(const float* __restrict__ ck, short* __restrict__ Bp){
    int p = blockIdx.x*256 + threadIdx.x;     // 147456 exact
    int L = p & 63;
    int nt = (p >> 6) & 31;
    int c32 = (p >> 11) & 7;
    int tap = p >> 14;
    int oc = nt*16 + (L & 15);
    int kq = L >> 4;
    short8 v;
    #pragma unroll
    for (int j=0;j<8;j++){
        int ic = c32*32 + kq*8 + j;
        v[j] = (short)f2bf(ck[(oc*256+ic)*9 + tap]);
    }
    *(short8*)&Bp[(long)p*8] = v;
}

// ---------------------------------------------------------------------------
// Pack X slice s (fp32) -> bf16 x-half of xh[row][0:128]; zero h-half at s==0
__global__ __launch_bounds__(256)
void k_pack_x(const float* __restrict__ X, short* __restrict__ xh, int s, int zero_h){
    int idx = blockIdx.x*256 + threadIdx.x;   // 131072
    int row = idx >> 4;
    int ch = (idx & 15) * 8;
    int b = row >> 10, hw = row & 1023;
    const float* src = X + (((long)(b*16+s)*1024 + hw)*128 + ch);
    float4 a = *(const float4*)src;
    float4 c = *(const float4*)(src+4);
    short8 v;
    v[0]=(short)f2bf(a.x); v[1]=(short)f2bf(a.y); v[2]=(short)f2bf(a.z); v[3]=(short)f2bf(a.w);
    v[4]=(short)f2bf(c.x); v[5]=(short)f2bf(c.y); v[6]=(short)f2bf(c.z); v[7]=(short)f2bf(c.w);
    *(short8*)&xh[(long)row*256 + ch] = v;
    if (zero_h){
        short8 z = {0,0,0,0,0,0,0,0};
        *(short8*)&xh[(long)row*256 + 128 + ch] = z;
    }
}

// ---------------------------------------------------------------------------
// Implicit-im2col MFMA GEMM: gates[8192][512] = patches(xh) @ W.
// Grid 512 = 128 Mblk x 4 Nblk. Mtile=64 (2 y-rows), Ntile=128 (one gate).
// 4 waves; wave w owns n-tiles {w*2, w*2+1}; acc[mt 0..3][nti 0..1] f32x4.
template<typename GT>
__global__ __launch_bounds__(256,2)
void k_conv_mfma(const short* __restrict__ xh, const short* __restrict__ Bp,
                 GT* __restrict__ gbuf){
    __shared__ short As[4096];                 // 512 packets x 16B, fragment order
    int tid = threadIdx.x;
    int Nblk = blockIdx.x & 3, Mblk = blockIdx.x >> 2;
    int b = Mblk >> 4, y0 = (Mblk & 15)*2;
    int w = tid >> 6, L = tid & 63;

    int pc_yl[2], pc_xl[2], pc_icb[2];
    #pragma unroll
    for (int pp=0; pp<2; pp++){
        int p = tid + pp*256;
        int mt = (p >> 6) & 3;
        int Lp = p & 63;
        int kq = Lp >> 4, lm = Lp & 15;
        int ml = mt*16 + lm;
        pc_yl[pp]  = ml >> 5;
        pc_xl[pp]  = ml & 31;
        pc_icb[pp] = (p >> 8)*32 + kq*8;       // c2*32 + kq*8
    }

    floatx4 acc[4][2];
    #pragma unroll
    for (int mt=0;mt<4;mt++)
        #pragma unroll
        for (int nti=0;nti<2;nti++)
            acc[mt][nti] = (floatx4){0.f,0.f,0.f,0.f};

    const short8* Bp8 = (const short8*)Bp;
    const short8* As8 = (const short8*)As;

    short8 va[2];
    // preload stage 0: tap=0 (dy=-1,dx=-1), sic=0
    #pragma unroll
    for (int pp=0; pp<2; pp++){
        int yy = y0 + pc_yl[pp] - 1;
        int xx = pc_xl[pp] - 1;
        short8 v = {0,0,0,0,0,0,0,0};
        if (yy>=0 && yy<32 && xx>=0 && xx<32)
            v = *(const short8*)&xh[((long)((b*32+yy)*32+xx)<<8) + pc_icb[pp]];
        va[pp] = v;
    }

    for (int stage=0; stage<36; stage++){      // 9 taps x 4 sic
        __syncthreads();
        *(short8*)&As[tid*8]       = va[0];
        *(short8*)&As[(tid+256)*8] = va[1];
        __syncthreads();

        if (stage+1 < 36){                     // prefetch next A-tile to VGPR
            int ns  = stage+1;
            int tap = ns >> 2, sic = ns & 3;
            int dy = tap/3 - 1, dx = tap - (tap/3)*3 - 1;
            #pragma unroll
            for (int pp=0; pp<2; pp++){
                int yy = y0 + pc_yl[pp] + dy;
                int xx = pc_xl[pp] + dx;
                short8 v = {0,0,0,0,0,0,0,0};
                if (yy>=0 && yy<32 && xx>=0 && xx<32)
                    v = *(const short8*)&xh[((long)((b*32+yy)*32+xx)<<8) + sic*64 + pc_icb[pp]];
                va[pp] = v;
            }
        }

        int tap = stage >> 2, sic = stage & 3;
        #pragma unroll
        for (int c2=0;c2<2;c2++){
            short8 bfr[2];
            #pragma unroll
            for (int nti=0;nti<2;nti++){
                int ntg = Nblk*8 + w*2 + nti;
                bfr[nti] = Bp8[((tap*8 + sic*2 + c2)*32 + ntg)*64 + L];
            }
            #pragma unroll
            for (int mt=0;mt<4;mt++){
                short8 afr = As8[(c2*4+mt)*64 + L];
                #pragma unroll
                for (int nti=0;nti<2;nti++)
                    acc[mt][nti] = __builtin_amdgcn_mfma_f32_16x16x32_bf16(afr, bfr[nti], acc[mt][nti], 0,0,0);
            }
        }
    }

    // epilogue: m = mt*16 + (L>>4)*4 + r, n = Nblk*128 + (w*2+nti)*16 + (L&15)
    int quad = L >> 4, lm16 = L & 15;
    #pragma unroll
    for (int mt=0;mt<4;mt++){
        #pragma unroll
        for (int nti=0;nti<2;nti++){
            int n = Nblk*128 + (w*2+nti)*16 + lm16;
            #pragma unroll
            for (int r=0;r<4;r++){
                long row = (long)Mblk*64 + mt*16 + quad*4 + r;
                st_gate(&gbuf[row*512 + n], acc[mt][nti][r]);
            }
        }
    }
}

// ---------------------------------------------------------------------------
// Fused LSTM pointwise: gates -> c_next, h_next (to d_out slice s + xh h-half)
template<typename GT>
__global__ __launch_bounds__(256)
void k_lstm(const GT* __restrict__ gbuf, float* __restrict__ cbuf,
            float* __restrict__ X, short* __restrict__ xh, int s){
    int idx = blockIdx.x*256 + threadIdx.x;    // 262144
    int row = idx >> 5;
    int c4 = (idx & 31)*4;
    float gi[4], gf[4], go[4], gg[4];
    const GT* gp = gbuf + (long)row*512 + c4;
    load_gate(gp,       gi);
    load_gate(gp + 128, gf);
    load_gate(gp + 256, go);
    load_gate(gp + 384, gg);
    float co[4];
    if (s == 0){ co[0]=co[1]=co[2]=co[3]=0.f; }
    else {
        float4 cv = *(const float4*)&cbuf[(long)row*128 + c4];
        co[0]=cv.x; co[1]=cv.y; co[2]=cv.z; co[3]=cv.w;
    }
    float cn[4], hn[4];
    #pragma unroll
    for (int j=0;j<4;j++){
        cn[j] = sigf(gf[j])*co[j] + sigf(gi[j])*tanh_fast(gg[j]);
        hn[j] = sigf(go[j])*tanh_fast(cn[j]);
    }
    *(float4*)&cbuf[(long)row*128 + c4] = make_float4(cn[0],cn[1],cn[2],cn[3]);
    int b = row >> 10, hw = row & 1023;
    long xoff = (((long)(b*16+s)*1024 + hw)*128) + c4;
    *(float4*)&X[xoff] = make_float4(hn[0],hn[1],hn[2],hn[3]);
    ushort4 hv;
    hv.x = f2bf(hn[0]); hv.y = f2bf(hn[1]); hv.z = f2bf(hn[2]); hv.w = f2bf(hn[3]);
    *(ushort4*)&xh[(long)row*256 + 128 + c4] = hv;
}

// ---------------------------------------------------------------------------
extern "C" void kernel_launch(void* const* d_in, const int* in_sizes, int n_in,
                              void* d_out, int out_size, void* d_ws, size_t ws_size,
                              hipStream_t stream){
    const float* inputs = (const float*)d_in[0];
    const float* Wp     = (const float*)d_in[1];
    const float* gamma  = (const float*)d_in[2];
    const float* beta   = (const float*)d_in[3];
    const float* Win    = (const float*)d_in[4];
    const float* Wout   = (const float*)d_in[5];
    const float* ck     = (const float*)d_in[6];
    float* X = (float*)d_out;

    char* ws = (char*)d_ws;
    const size_t szB  = 147456ull*16;          // 2,359,296  B-fragment packets
    const size_t szXH = 8192ull*256*2;         // 4,194,304  bf16 [x|h] plane
    const size_t szC  = 8192ull*128*4;         // 4,194,304  fp32 cell state
    short* Bp   = (short*)(ws);
    short* xh   = (short*)(ws + szB);
    float* cbuf = (float*)(ws + szB + szXH);
    char*  gch  =         ws + szB + szXH + szC;
    bool gate_f32 = ws_size >= (szB + szXH + szC + 8192ull*512*4);

    k_pack_w<<<576, 256, 0, stream>>>(ck, Bp);
    k_proj_ln<<<NTOK/8, 128, 0, stream>>>(inputs, Wp, gamma, beta, X);
    k_attn<<<B_*HW_, 384, 0, stream>>>(X, Win, Wout, inputs, X);  // in-place

    if (gate_f32){
        float* gbuf = (float*)gch;
        for (int s=0; s<16; s++){
            k_pack_x<<<512, 256, 0, stream>>>(X, xh, s, s==0);
            k_conv_mfma<float><<<512, 256, 0, stream>>>(xh, Bp, gbuf);
            k_lstm<float><<<1024, 256, 0, stream>>>(gbuf, cbuf, X, xh, s);
        }
    } else {
        unsigned short* gbuf = (unsigned short*)gch;
        for (int s=0; s<16; s++){
            k_pack_x<<<512, 256, 0, stream>>>(X, xh, s, s==0);
            k_conv_mfma<unsigned short><<<512, 256, 0, stream>>>(xh, Bp, gbuf);
            k_lstm<unsigned short><<<1024, 256, 0, stream>>>(gbuf, cbuf, X, xh, s);
        }
    }
}

// Round 5
// 1336.645 us; speedup vs baseline: 25.8275x; 1.5229x over previous
//
#include <hip/hip_runtime.h>
#include <math.h>

#define B_  8
#define S_  16
#define H_  32
#define W_  32
#define E_  128
#define NH_ 8
#define HD_ 16
#define HW_ (H_*W_)            // 1024
#define NTOK (B_*S_*H_*W_)     // 131072

typedef __attribute__((ext_vector_type(8))) short short8;
typedef __attribute__((ext_vector_type(4))) short short4v;
typedef __attribute__((ext_vector_type(4))) float floatx4;

__device__ __forceinline__ float sigf(float x){
    return 1.f/(1.f+__expf(-x));
}
__device__ __forceinline__ float tanh_fast(float x){
    x = fminf(fmaxf(x, -15.f), 15.f);
    float e = __expf(2.f*x);
    return (e-1.f)/(e+1.f);
}
__device__ __forceinline__ unsigned short f2bf(float f){
    unsigned int u = __float_as_uint(f);
    u = (u + 0x7fffu + ((u >> 16) & 1u)) >> 16;   // RNE
    return (unsigned short)u;
}
__device__ __forceinline__ float bf2f(unsigned short h){
    return __uint_as_float(((unsigned int)h) << 16);
}

__device__ __forceinline__ void st_gate(float* p, float v){ *p = v; }
__device__ __forceinline__ void st_gate(unsigned short* p, float v){ *p = f2bf(v); }
__device__ __forceinline__ void load_gate(const float* p, float* o){
    float4 v = *(const float4*)p; o[0]=v.x; o[1]=v.y; o[2]=v.z; o[3]=v.w;
}
__device__ __forceinline__ void load_gate(const unsigned short* p, float* o){
    ushort4 v = *(const ushort4*)p;
    o[0]=bf2f(v.x); o[1]=bf2f(v.y); o[2]=bf2f(v.z); o[3]=bf2f(v.w);
}

// ---------------------------------------------------------------------------
// X = LayerNorm(silu(inputs @ W_proj)) ; 8 rows per block, 128 threads
__global__ __launch_bounds__(128)
void k_proj_ln(const float* __restrict__ in, const float* __restrict__ Wp,
               const float* __restrict__ gamma, const float* __restrict__ beta,
               float* __restrict__ X){
    __shared__ float xin[8][128];
    __shared__ float red[2][8][2];
    int tid = threadIdx.x;
    long r0 = (long)blockIdx.x * 8;
    #pragma unroll
    for (int r=0;r<8;r++) xin[r][tid] = in[(r0+r)*128 + tid];
    __syncthreads();

    float acc[8] = {0,0,0,0,0,0,0,0};
    for (int k=0;k<128;k+=4){
        float w0 = Wp[(k+0)*128+tid];
        float w1 = Wp[(k+1)*128+tid];
        float w2 = Wp[(k+2)*128+tid];
        float w3 = Wp[(k+3)*128+tid];
        #pragma unroll
        for (int r=0;r<8;r++){
            float4 xv = *(const float4*)&xin[r][k];
            acc[r] += xv.x*w0 + xv.y*w1 + xv.z*w2 + xv.w*w3;
        }
    }
    #pragma unroll
    for (int r=0;r<8;r++){ float a = acc[r]; acc[r] = a*sigf(a); }   // silu

    int lane = tid & 63, wid = tid >> 6;
    #pragma unroll
    for (int r=0;r<8;r++){
        float s1 = acc[r], s2 = acc[r]*acc[r];
        #pragma unroll
        for (int off=32; off>0; off>>=1){
            s1 += __shfl_down(s1, off);
            s2 += __shfl_down(s2, off);
        }
        if (lane==0){ red[wid][r][0] = s1; red[wid][r][1] = s2; }
    }
    __syncthreads();
    float g = gamma[tid], bb = beta[tid];
    #pragma unroll
    for (int r=0;r<8;r++){
        float s1 = red[0][r][0] + red[1][r][0];
        float s2 = red[0][r][1] + red[1][r][1];
        float mu  = s1 * (1.f/128.f);
        float var = s2 * (1.f/128.f) - mu*mu;
        float y = (acc[r]-mu)*rsqrtf(var + 1e-5f)*g + bb;
        X[(r0+r)*128 + tid] = y;
    }
}

// ---------------------------------------------------------------------------
// W_in (128x384) -> bf16 B-fragment packets: packet (nt*4+kc)*64+L holds
// B[k=kc*32+(L>>4)*8+j][n=nt*16+(L&15)], j=0..7
__global__ __launch_bounds__(256)
void k_pack_win(const float* __restrict__ Win, short* __restrict__ Winp){
    int p = blockIdx.x*256 + threadIdx.x;    // 6144 packets
    int L = p & 63;
    int idx = p >> 6;                        // nt*4+kc
    int nt = idx >> 2, kc = idx & 3;
    int n = nt*16 + (L & 15);
    int k0 = kc*32 + (L >> 4)*8;
    short8 v;
    #pragma unroll
    for (int j=0;j<8;j++) v[j] = (short)f2bf(Win[(k0+j)*384 + n]);
    *(short8*)&Winp[(long)p*8] = v;
}

// ---------------------------------------------------------------------------
// W_out (128x128) -> per-head zero-padded B packets: packet (h*8+nt)*64+L:
// B[k=(L>>4)*8+j][n=nt*16+(L&15)] = (k<16) ? Wout[h*16+k][n] : 0
__global__ __launch_bounds__(256)
void k_pack_wout(const float* __restrict__ Wout, short* __restrict__ Woutp){
    int p = blockIdx.x*256 + threadIdx.x;    // 4096 packets
    int L = p & 63;
    int idx = p >> 6;                        // h*8+nt
    int h = idx >> 3, nt = idx & 7;
    int n = nt*16 + (L & 15);
    int k0 = (L >> 4)*8;
    short8 v;
    #pragma unroll
    for (int j=0;j<8;j++){
        int k = k0 + j;
        v[j] = (k < 16) ? (short)f2bf(Wout[(h*16+k)*128 + n]) : (short)0;
    }
    *(short8*)&Woutp[(long)p*8] = v;
}

// ---------------------------------------------------------------------------
// Fused MFMA attention. Block = (b, 8 hw-sites), M=128 rows (site*16+s).
// 4 waves, each owns 2 sites; ALL LDS traffic is wave-local (no barriers).
// NOTE head h's q/k/v = W_in columns h*48+{0,16,32}.. i.e. n-tiles 3h,3h+1,3h+2
// (reshape (...,NH,3*HD) THEN split) — R4 bug was nt=h,8+h,16+h.
__global__ __launch_bounds__(256,2)
void k_attn_mfma(const float* __restrict__ X, const short* __restrict__ Winp,
                 const short* __restrict__ Woutp, const float* __restrict__ resid,
                 float* __restrict__ Y){
    __shared__ short lds[31872];             // 63,744 B
    const int XO=0;                          // X tile  [128][136]
    const int QO=17408;                      // Q plain [128][24]
    const int KO=20480;                      // K plain [128][24]
    const int VO=23552;                      // V^T     [16][136] (cols = m)
    const int PO=25728;                      // P plain [128][24]
    const int AOO=28800;                     // ao      [128][24]
    int tid = threadIdx.x;
    int w = tid >> 6, L = tid & 63;
    int quad = L >> 4, lm = L & 15;
    int b = blockIdx.x >> 7, tile = blockIdx.x & 127;
    int hw0 = tile * 8;

    // phase 1: wave-local X rows w*32..w*32+31 (sites 2w, 2w+1), fp32->bf16
    {
        int cq = L & 31, rh = L >> 5;
        for (int p=0; p<16; p++){
            int m = w*32 + p*2 + rh;
            int s = m & 15, st = m >> 4;
            float4 v = *(const float4*)&X[((((long)b*16 + s)*1024) + hw0 + st)*128 + cq*4];
            short4v hv;
            hv[0]=(short)f2bf(v.x); hv[1]=(short)f2bf(v.y);
            hv[2]=(short)f2bf(v.z); hv[3]=(short)f2bf(v.w);
            *(short4v*)&lds[XO + m*136 + cq*4] = hv;
        }
    }

    floatx4 Oa[2][8];
    #pragma unroll
    for (int mt=0;mt<2;mt++)
        #pragma unroll
        for (int nt=0;nt<8;nt++) Oa[mt][nt] = (floatx4){0.f,0.f,0.f,0.f};

    const floatx4 zc = (floatx4){0.f,0.f,0.f,0.f};
    const short8 z8 = {0,0,0,0,0,0,0,0};

    for (int h=0; h<8; h++){
        // ---- phase 2: QKV GEMM for n-tiles {3h, 3h+1, 3h+2} = q,k,v of head h
        floatx4 qacc[2][3];
        #pragma unroll
        for (int mt=0;mt<2;mt++)
            #pragma unroll
            for (int t=0;t<3;t++) qacc[mt][t] = zc;
        #pragma unroll
        for (int kc=0;kc<4;kc++){
            short8 af[2];
            #pragma unroll
            for (int mt=0;mt<2;mt++)
                af[mt] = *(const short8*)&lds[XO + (w*32+mt*16+lm)*136 + kc*32 + quad*8];
            #pragma unroll
            for (int t=0;t<3;t++){
                int nt = 3*h + t;
                short8 bf = *(const short8*)&Winp[(long)((nt*4+kc)*64 + L)*8];
                #pragma unroll
                for (int mt=0;mt<2;mt++)
                    qacc[mt][t] = __builtin_amdgcn_mfma_f32_16x16x32_bf16(af[mt], bf, qacc[mt][t], 0,0,0);
            }
        }
        // epilogue: Q,K -> plain [m][d]; V -> V^T [d][m]
        #pragma unroll
        for (int mt=0;mt<2;mt++){
            int m0 = w*32 + mt*16;
            #pragma unroll
            for (int r=0;r<4;r++){
                lds[QO + (m0+quad*4+r)*24 + lm] = (short)f2bf(qacc[mt][0][r]);
                lds[KO + (m0+quad*4+r)*24 + lm] = (short)f2bf(qacc[mt][1][r]);
            }
            short4v vv;
            #pragma unroll
            for (int r=0;r<4;r++) vv[r] = (short)f2bf(qacc[mt][2][r]);
            *(short4v*)&lds[VO + lm*136 + m0 + quad*4] = vv;
        }

        // ---- phase 3: per-site scores -> softmax -> PV ----
        #pragma unroll
        for (int mt=0;mt<2;mt++){
            int sb = w*32 + mt*16;
            short8 qf = z8, kf = z8;
            if (quad < 2){
                qf = *(const short8*)&lds[QO + (sb+lm)*24 + quad*8];
                kf = *(const short8*)&lds[KO + (sb+lm)*24 + quad*8];
            }
            floatx4 scv = __builtin_amdgcn_mfma_f32_16x16x32_bf16(qf, kf, zc, 0,0,0);
            float pv[4], mr[4];
            #pragma unroll
            for (int r=0;r<4;r++){
                int si = quad*4 + r;
                pv[r] = scv[r]*0.25f + (lm <= si ? 1.0f : -1000.0f);
                mr[r] = pv[r];
            }
            #pragma unroll
            for (int d=1; d<16; d<<=1)
                #pragma unroll
                for (int r=0;r<4;r++) mr[r] = fmaxf(mr[r], __shfl_xor(mr[r], d));
            float ex[4], sm[4];
            #pragma unroll
            for (int r=0;r<4;r++){ ex[r] = __expf(pv[r]-mr[r]); sm[r] = ex[r]; }
            #pragma unroll
            for (int d=1; d<16; d<<=1)
                #pragma unroll
                for (int r=0;r<4;r++) sm[r] += __shfl_xor(sm[r], d);
            #pragma unroll
            for (int r=0;r<4;r++)
                lds[PO + (sb+quad*4+r)*24 + lm] = (short)f2bf(ex[r]/sm[r]);

            short8 pf = z8, vf = z8;
            if (quad < 2){
                pf = *(const short8*)&lds[PO + (sb+lm)*24 + quad*8];
                vf = *(const short8*)&lds[VO + lm*136 + sb + quad*8];
            }
            floatx4 aov = __builtin_amdgcn_mfma_f32_16x16x32_bf16(pf, vf, zc, 0,0,0);
            #pragma unroll
            for (int r=0;r<4;r++)
                lds[AOO + (sb+quad*4+r)*24 + lm] = (short)f2bf(aov[r]);
        }

        // ---- phase 4: O += ao_h @ Wout[h-rows] ----
        #pragma unroll
        for (int mt=0;mt<2;mt++){
            short8 aof = z8;
            if (quad < 2)
                aof = *(const short8*)&lds[AOO + (w*32+mt*16+lm)*24 + quad*8];
            #pragma unroll
            for (int nt=0;nt<8;nt++){
                short8 wf = *(const short8*)&Woutp[(long)((h*8+nt)*64 + L)*8];
                Oa[mt][nt] = __builtin_amdgcn_mfma_f32_16x16x32_bf16(aof, wf, Oa[mt][nt], 0,0,0);
            }
        }
    }

    // epilogue: O + residual -> Y (in place over X rows this block loaded)
    #pragma unroll
    for (int mt=0;mt<2;mt++){
        int hw = hw0 + w*2 + mt;
        #pragma unroll
        for (int nt=0;nt<8;nt++){
            int n = nt*16 + lm;
            #pragma unroll
            for (int r=0;r<4;r++){
                int s = quad*4 + r;
                long addr = (((long)b*16 + s)*1024 + hw)*128 + n;
                Y[addr] = Oa[mt][nt][r] + resid[addr];
            }
        }
    }
}

// ---------------------------------------------------------------------------
// Weights -> B-fragment packets, bf16 (conv GEMM).
__global__ __launch_bounds__(256)
void k_pack_w(const float* __restrict__ ck, short* __restrict__ Bp){
    int p = blockIdx.x*256 + threadIdx.x;     // 147456 exact
    int L = p & 63;
    int nt = (p >> 6) & 31;
    int c32 = (p >> 11) & 7;
    int tap = p >> 14;
    int oc = nt*16 + (L & 15);
    int kq = L >> 4;
    short8 v;
    #pragma unroll
    for (int j=0;j<8;j++){
        int ic = c32*32 + kq*8 + j;
        v[j] = (short)f2bf(ck[(oc*256+ic)*9 + tap]);
    }
    *(short8*)&Bp[(long)p*8] = v;
}

// ---------------------------------------------------------------------------
// Pack X slice s (fp32) -> bf16 x-half of xh[row][0:128]; zero h-half at s==0
__global__ __launch_bounds__(256)
void k_pack_x(const float* __restrict__ X, short* __restrict__ xh, int s, int zero_h){
    int idx = blockIdx.x*256 + threadIdx.x;   // 131072
    int row = idx >> 4;
    int ch = (idx & 15) * 8;
    int b = row >> 10, hw = row & 1023;
    const float* src = X + (((long)(b*16+s)*1024 + hw)*128 + ch);
    float4 a = *(const float4*)src;
    float4 c = *(const float4*)(src+4);
    short8 v;
    v[0]=(short)f2bf(a.x); v[1]=(short)f2bf(a.y); v[2]=(short)f2bf(a.z); v[3]=(short)f2bf(a.w);
    v[4]=(short)f2bf(c.x); v[5]=(short)f2bf(c.y); v[6]=(short)f2bf(c.z); v[7]=(short)f2bf(c.w);
    *(short8*)&xh[(long)row*256 + ch] = v;
    if (zero_h){
        short8 z = {0,0,0,0,0,0,0,0};
        *(short8*)&xh[(long)row*256 + 128 + ch] = z;
    }
}

// ---------------------------------------------------------------------------
// Implicit-im2col MFMA GEMM: gates[8192][512] = patches(xh) @ W.
template<typename GT>
__global__ __launch_bounds__(256,2)
void k_conv_mfma(const short* __restrict__ xh, const short* __restrict__ Bp,
                 GT* __restrict__ gbuf){
    __shared__ short As[4096];
    int tid = threadIdx.x;
    int Nblk = blockIdx.x & 3, Mblk = blockIdx.x >> 2;
    int b = Mblk >> 4, y0 = (Mblk & 15)*2;
    int w = tid >> 6, L = tid & 63;

    int pc_yl[2], pc_xl[2], pc_icb[2];
    #pragma unroll
    for (int pp=0; pp<2; pp++){
        int p = tid + pp*256;
        int mt = (p >> 6) & 3;
        int Lp = p & 63;
        int kq = Lp >> 4, lmm = Lp & 15;
        int ml = mt*16 + lmm;
        pc_yl[pp]  = ml >> 5;
        pc_xl[pp]  = ml & 31;
        pc_icb[pp] = (p >> 8)*32 + kq*8;
    }

    floatx4 acc[4][2];
    #pragma unroll
    for (int mt=0;mt<4;mt++)
        #pragma unroll
        for (int nti=0;nti<2;nti++)
            acc[mt][nti] = (floatx4){0.f,0.f,0.f,0.f};

    const short8* Bp8 = (const short8*)Bp;
    const short8* As8 = (const short8*)As;

    short8 va[2];
    #pragma unroll
    for (int pp=0; pp<2; pp++){
        int yy = y0 + pc_yl[pp] - 1;
        int xx = pc_xl[pp] - 1;
        short8 v = {0,0,0,0,0,0,0,0};
        if (yy>=0 && yy<32 && xx>=0 && xx<32)
            v = *(const short8*)&xh[((long)((b*32+yy)*32+xx)<<8) + pc_icb[pp]];
        va[pp] = v;
    }

    for (int stage=0; stage<36; stage++){
        __syncthreads();
        *(short8*)&As[tid*8]       = va[0];
        *(short8*)&As[(tid+256)*8] = va[1];
        __syncthreads();

        if (stage+1 < 36){
            int ns  = stage+1;
            int tap = ns >> 2, sic = ns & 3;
            int dy = tap/3 - 1, dx = tap - (tap/3)*3 - 1;
            #pragma unroll
            for (int pp=0; pp<2; pp++){
                int yy = y0 + pc_yl[pp] + dy;
                int xx = pc_xl[pp] + dx;
                short8 v = {0,0,0,0,0,0,0,0};
                if (yy>=0 && yy<32 && xx>=0 && xx<32)
                    v = *(const short8*)&xh[((long)((b*32+yy)*32+xx)<<8) + sic*64 + pc_icb[pp]];
                va[pp] = v;
            }
        }

        int tap = stage >> 2, sic = stage & 3;
        #pragma unroll
        for (int c2=0;c2<2;c2++){
            short8 bfr[2];
            #pragma unroll
            for (int nti=0;nti<2;nti++){
                int ntg = Nblk*8 + w*2 + nti;
                bfr[nti] = Bp8[((tap*8 + sic*2 + c2)*32 + ntg)*64 + L];
            }
            #pragma unroll
            for (int mt=0;mt<4;mt++){
                short8 afr = As8[(c2*4+mt)*64 + L];
                #pragma unroll
                for (int nti=0;nti<2;nti++)
                    acc[mt][nti] = __builtin_amdgcn_mfma_f32_16x16x32_bf16(afr, bfr[nti], acc[mt][nti], 0,0,0);
            }
        }
    }

    int quad = L >> 4, lm16 = L & 15;
    #pragma unroll
    for (int mt=0;mt<4;mt++){
        #pragma unroll
        for (int nti=0;nti<2;nti++){
            int n = Nblk*128 + (w*2+nti)*16 + lm16;
            #pragma unroll
            for (int r=0;r<4;r++){
                long row = (long)Mblk*64 + mt*16 + quad*4 + r;
                st_gate(&gbuf[row*512 + n], acc[mt][nti][r]);
            }
        }
    }
}

// ---------------------------------------------------------------------------
// Fused LSTM pointwise
template<typename GT>
__global__ __launch_bounds__(256)
void k_lstm(const GT* __restrict__ gbuf, float* __restrict__ cbuf,
            float* __restrict__ X, short* __restrict__ xh, int s){
    int idx = blockIdx.x*256 + threadIdx.x;    // 262144
    int row = idx >> 5;
    int c4 = (idx & 31)*4;
    float gi[4], gf[4], go[4], gg[4];
    const GT* gp = gbuf + (long)row*512 + c4;
    load_gate(gp,       gi);
    load_gate(gp + 128, gf);
    load_gate(gp + 256, go);
    load_gate(gp + 384, gg);
    float co[4];
    if (s == 0){ co[0]=co[1]=co[2]=co[3]=0.f; }
    else {
        float4 cv = *(const float4*)&cbuf[(long)row*128 + c4];
        co[0]=cv.x; co[1]=cv.y; co[2]=cv.z; co[3]=cv.w;
    }
    float cn[4], hn[4];
    #pragma unroll
    for (int j=0;j<4;j++){
        cn[j] = sigf(gf[j])*co[j] + sigf(gi[j])*tanh_fast(gg[j]);
        hn[j] = sigf(go[j])*tanh_fast(cn[j]);
    }
    *(float4*)&cbuf[(long)row*128 + c4] = make_float4(cn[0],cn[1],cn[2],cn[3]);
    int b = row >> 10, hw = row & 1023;
    long xoff = (((long)(b*16+s)*1024 + hw)*128) + c4;
    *(float4*)&X[xoff] = make_float4(hn[0],hn[1],hn[2],hn[3]);
    ushort4 hv;
    hv.x = f2bf(hn[0]); hv.y = f2bf(hn[1]); hv.z = f2bf(hn[2]); hv.w = f2bf(hn[3]);
    *(ushort4*)&xh[(long)row*256 + 128 + c4] = hv;
}

// ---------------------------------------------------------------------------
extern "C" void kernel_launch(void* const* d_in, const int* in_sizes, int n_in,
                              void* d_out, int out_size, void* d_ws, size_t ws_size,
                              hipStream_t stream){
    const float* inputs = (const float*)d_in[0];
    const float* Wp     = (const float*)d_in[1];
    const float* gamma  = (const float*)d_in[2];
    const float* beta   = (const float*)d_in[3];
    const float* Win    = (const float*)d_in[4];
    const float* Wout   = (const float*)d_in[5];
    const float* ck     = (const float*)d_in[6];
    float* X = (float*)d_out;

    char* ws = (char*)d_ws;
    const size_t szB    = 147456ull*16;        // 2,359,296
    const size_t szXH   = 8192ull*256*2;       // 4,194,304
    const size_t szC    = 8192ull*128*4;       // 4,194,304
    const size_t szWin  = 6144ull*16;          //    98,304
    const size_t szWout = 4096ull*16;          //    65,536
    short* Bp    = (short*)(ws);
    short* xh    = (short*)(ws + szB);
    float* cbuf  = (float*)(ws + szB + szXH);
    short* Winp  = (short*)(ws + szB + szXH + szC);
    short* Woutp = (short*)(ws + szB + szXH + szC + szWin);
    char*  gch   =         ws + szB + szXH + szC + szWin + szWout;
    bool gate_f32 = ws_size >= (szB + szXH + szC + szWin + szWout + 8192ull*512*4);

    k_pack_w<<<576, 256, 0, stream>>>(ck, Bp);
    k_pack_win<<<24, 256, 0, stream>>>(Win, Winp);
    k_pack_wout<<<16, 256, 0, stream>>>(Wout, Woutp);
    k_proj_ln<<<NTOK/8, 128, 0, stream>>>(inputs, Wp, gamma, beta, X);
    k_attn_mfma<<<1024, 256, 0, stream>>>(X, Winp, Woutp, inputs, X);  // in-place

    if (gate_f32){
        float* gbuf = (float*)gch;
        for (int s=0; s<16; s++){
            k_pack_x<<<512, 256, 0, stream>>>(X, xh, s, s==0);
            k_conv_mfma<float><<<512, 256, 0, stream>>>(xh, Bp, gbuf);
            k_lstm<float><<<1024, 256, 0, stream>>>(gbuf, cbuf, X, xh, s);
        }
    } else {
        unsigned short* gbuf = (unsigned short*)gch;
        for (int s=0; s<16; s++){
            k_pack_x<<<512, 256, 0, stream>>>(X, xh, s, s==0);
            k_conv_mfma<unsigned short><<<512, 256, 0, stream>>>(xh, Bp, gbuf);
            k_lstm<unsigned short><<<1024, 256, 0, stream>>>(gbuf, cbuf, X, xh, s);
        }
    }
}